// Round 1
// baseline (1111.369 us; speedup 1.0000x reference)
//
#include <hip/hip_runtime.h>
#include <hip/hip_bf16.h>

#define DFEAT 128

// ---------------- degree count ----------------
__global__ void deg_kernel(const int* __restrict__ ei, int* __restrict__ deg, int E) {
    int e = blockIdx.x * blockDim.x + threadIdx.x;
    if (e < E) {
        int r = ei[e];
        int c = ei[E + e];
        if (r != c) atomicAdd(&deg[r], 1);
    }
}

// ---------------- dinv ----------------
__global__ void dinv_kernel(const int* __restrict__ deg, float* __restrict__ dinv, int n) {
    int i = blockIdx.x * blockDim.x + threadIdx.x;
    if (i < n) {
        int d = deg[i];
        dinv[i] = (d > 0) ? rsqrtf((float)d) : 0.f;
    }
}

// ---------------- exclusive scan -> row_ptr (single block, wave-scan based) ----------------
__global__ __launch_bounds__(1024) void scan_kernel(const int* __restrict__ deg, int* __restrict__ row_ptr, int n) {
    __shared__ int wsums[16];
    __shared__ int s_chunk;
    __shared__ int s_carry;
    int t = threadIdx.x;
    if (t == 0) { s_carry = 0; row_ptr[0] = 0; }
    __syncthreads();
    for (int base = 0; base < n; base += 1024) {
        int idx = base + t;
        int v = (idx < n) ? deg[idx] : 0;
        int vi = v;
        #pragma unroll
        for (int off = 1; off < 64; off <<= 1) {
            int x = __shfl_up(vi, off);
            if ((t & 63) >= off) vi += x;
        }
        if ((t & 63) == 63) wsums[t >> 6] = vi;
        __syncthreads();
        if (t < 16) {
            int s = wsums[t];
            int si = s;
            #pragma unroll
            for (int off = 1; off < 16; off <<= 1) {
                int x = __shfl_up(si, off);
                if (t >= off) si += x;
            }
            wsums[t] = si - s;           // exclusive prefix of wave sums
            if (t == 15) s_chunk = si;   // chunk total
        }
        __syncthreads();
        if (idx < n) row_ptr[idx + 1] = s_carry + wsums[t >> 6] + vi;
        __syncthreads();
        if (t == 0) s_carry += s_chunk;
        __syncthreads();
    }
}

// ---------------- CSR fill with edge weights ----------------
__global__ void fill_kernel(const int* __restrict__ ei, const int* __restrict__ row_ptr,
                            int* __restrict__ fillc, const float* __restrict__ dinv,
                            int* __restrict__ e_col, float* __restrict__ e_w, int E) {
    int e = blockIdx.x * blockDim.x + threadIdx.x;
    if (e < E) {
        int r = ei[e];
        int c = ei[E + e];
        if (r != c) {
            int pos = row_ptr[r] + atomicAdd(&fillc[r], 1);
            e_col[pos] = c;
            e_w[pos] = -dinv[r] * dinv[c];
        }
    }
}

// ---------------- sparse prop: out[i,:] = alpha * sum_e w*in[col,:] (- sub[i,:]) ----------------
__global__ __launch_bounds__(128) void prop_kernel(
    const float* __restrict__ hin, const float* __restrict__ sub,
    float* __restrict__ hout,
    const int* __restrict__ row_ptr, const int* __restrict__ e_col,
    const float* __restrict__ e_w, float alpha, int n)
{
    int i = blockIdx.x;
    int f = threadIdx.x;
    __shared__ int sc[128];
    __shared__ float sw[128];
    int s = row_ptr[i];
    int e = row_ptr[i + 1];
    float acc = 0.f;
    for (int base = s; base < e; base += 128) {
        int m = e - base; if (m > 128) m = 128;
        if (f < m) { sc[f] = e_col[base + f]; sw[f] = e_w[base + f]; }
        __syncthreads();
        for (int j = 0; j < m; ++j)
            acc += sw[j] * hin[(size_t)sc[j] * DFEAT + f];
        __syncthreads();
    }
    float r = alpha * acc;
    if (sub) r -= sub[(size_t)i * DFEAT + f];
    hout[(size_t)i * DFEAT + f] = r;
}

// ---------------- fused 3-way GEMM + bias + ReLU ----------------
// out[i,:] = relu( X0[i,:]@W[0] + X1[i,:]@W[1] + X2[i,:]@W[2] + b )
// 64-row x 128-col tile per block; 256 threads; 8x4 micro-tile per thread.
// In-place (out==X0) is safe: block only reads/writes its own rows.
__global__ __launch_bounds__(256) void gemm3_relu_kernel(
    const float* __restrict__ X0, const float* __restrict__ X1, const float* __restrict__ X2,
    const float* __restrict__ W, const float* __restrict__ bias,
    float* __restrict__ out, int n)
{
    __shared__ float Xs[64][20];    // 16-k chunk, padded (80B rows keep 16B alignment)
    __shared__ float Ws[16][128];
    const int t = threadIdx.x;
    const int tx = t & 31;          // cols tx*4 .. tx*4+3
    const int ty = t >> 5;          // rows ty*8 .. ty*8+7
    const int row0 = blockIdx.x * 64;

    float4 acc[8];
    #pragma unroll
    for (int i = 0; i < 8; ++i) acc[i] = make_float4(0.f, 0.f, 0.f, 0.f);

    const int lrow = t >> 2;        // 0..63
    const int lkq  = t & 3;         // 0..3
    int grow = row0 + lrow; if (grow >= n) grow = n - 1;

    #pragma unroll
    for (int seg = 0; seg < 3; ++seg) {
        const float* Xp = (seg == 0) ? X0 : ((seg == 1) ? X1 : X2);
        const float* Wp = W + (size_t)seg * DFEAT * DFEAT;
        for (int k0 = 0; k0 < DFEAT; k0 += 16) {
            __syncthreads();
            // stage X chunk: 64 rows x 16 k
            float4 xv4 = *(const float4*)&Xp[(size_t)grow * DFEAT + k0 + lkq * 4];
            Xs[lrow][lkq * 4 + 0] = xv4.x;
            Xs[lrow][lkq * 4 + 1] = xv4.y;
            Xs[lrow][lkq * 4 + 2] = xv4.z;
            Xs[lrow][lkq * 4 + 3] = xv4.w;
            // stage W chunk: 16 rows x 128 cols (2 float4 per thread)
            {
                int wr = t >> 5;
                *(float4*)&Ws[wr][(t & 31) * 4] =
                    *(const float4*)&Wp[(size_t)(k0 + wr) * DFEAT + (t & 31) * 4];
                int idx2 = t + 256;
                int wr2 = idx2 >> 5;
                *(float4*)&Ws[wr2][(idx2 & 31) * 4] =
                    *(const float4*)&Wp[(size_t)(k0 + wr2) * DFEAT + (idx2 & 31) * 4];
            }
            __syncthreads();
            #pragma unroll
            for (int kq = 0; kq < 4; ++kq) {
                float4 w0 = *(const float4*)&Ws[kq * 4 + 0][tx * 4];
                float4 w1 = *(const float4*)&Ws[kq * 4 + 1][tx * 4];
                float4 w2 = *(const float4*)&Ws[kq * 4 + 2][tx * 4];
                float4 w3 = *(const float4*)&Ws[kq * 4 + 3][tx * 4];
                #pragma unroll
                for (int i = 0; i < 8; ++i) {
                    float4 xv = *(const float4*)&Xs[ty * 8 + i][kq * 4];
                    acc[i].x += xv.x * w0.x + xv.y * w1.x + xv.z * w2.x + xv.w * w3.x;
                    acc[i].y += xv.x * w0.y + xv.y * w1.y + xv.z * w2.y + xv.w * w3.y;
                    acc[i].z += xv.x * w0.z + xv.y * w1.z + xv.z * w2.z + xv.w * w3.z;
                    acc[i].w += xv.x * w0.w + xv.y * w1.w + xv.z * w2.w + xv.w * w3.w;
                }
            }
        }
    }
    float4 bv = *(const float4*)&bias[tx * 4];
    #pragma unroll
    for (int i = 0; i < 8; ++i) {
        int r = row0 + ty * 8 + i;
        if (r < n) {
            float4 o;
            o.x = fmaxf(acc[i].x + bv.x, 0.f);
            o.y = fmaxf(acc[i].y + bv.y, 0.f);
            o.z = fmaxf(acc[i].z + bv.z, 0.f);
            o.w = fmaxf(acc[i].w + bv.w, 0.f);
            *(float4*)&out[(size_t)r * DFEAT + tx * 4] = o;
        }
    }
}

extern "C" void kernel_launch(void* const* d_in, const int* in_sizes, int n_in,
                              void* d_out, int out_size, void* d_ws, size_t ws_size,
                              hipStream_t stream) {
    const float* x  = (const float*)d_in[0];
    const int*   ei = (const int*)d_in[1];
    const float* W1 = (const float*)d_in[2];
    const float* b1 = (const float*)d_in[3];
    const float* W2 = (const float*)d_in[4];
    const float* b2 = (const float*)d_in[5];
    const float* W3 = (const float*)d_in[6];
    const float* b3 = (const float*)d_in[7];
    float* out = (float*)d_out;

    const int N = in_sizes[0] / DFEAT;   // 50000
    const int E = in_sizes[1] / 2;       // 800000

    // workspace layout
    float* A   = (float*)d_ws;
    float* T1  = A  + (size_t)N * DFEAT;
    float* T2  = T1 + (size_t)N * DFEAT;
    int*   deg = (int*)(T2 + (size_t)N * DFEAT);
    int*   fillc   = deg + N;
    int*   row_ptr = fillc + N;
    float* dinv    = (float*)(row_ptr + (N + 1));
    int*   e_col   = (int*)(dinv + N);
    float* e_w     = (float*)(e_col + E);

    hipMemsetAsync(deg,   0, sizeof(int) * N, stream);
    hipMemsetAsync(fillc, 0, sizeof(int) * N, stream);

    deg_kernel<<<(E + 255) / 256, 256, 0, stream>>>(ei, deg, E);
    scan_kernel<<<1, 1024, 0, stream>>>(deg, row_ptr, N);
    dinv_kernel<<<(N + 255) / 256, 256, 0, stream>>>(deg, dinv, N);
    fill_kernel<<<(E + 255) / 256, 256, 0, stream>>>(ei, row_ptr, fillc, dinv, e_col, e_w, E);

    const float* Wl[3] = {W1, W2, W3};
    const float* bl[3] = {b1, b2, b3};
    const float* hin = x;
    for (int l = 0; l < 3; ++l) {
        float* hout = (l == 2) ? out : A;
        // Tx1 = L_hat @ h
        prop_kernel<<<N, 128, 0, stream>>>(hin, nullptr, T1, row_ptr, e_col, e_w, 1.f, N);
        // Tx2 = 2 * L_hat @ Tx1 - h
        prop_kernel<<<N, 128, 0, stream>>>(T1, hin, T2, row_ptr, e_col, e_w, 2.f, N);
        // out = relu(h@W0 + Tx1@W1 + Tx2@W2 + b)
        gemm3_relu_kernel<<<(N + 63) / 64, 256, 0, stream>>>(hin, T1, T2, Wl[l], bl[l], hout, N);
        hin = hout;
    }
}

// Round 2
// 724.404 us; speedup vs baseline: 1.5342x; 1.5342x over previous
//
#include <hip/hip_runtime.h>
#include <hip/hip_bf16.h>

#define DFEAT 128

typedef short bf16x8 __attribute__((ext_vector_type(8)));
typedef float f32x4  __attribute__((ext_vector_type(4)));

__device__ __forceinline__ unsigned bf16r(float f) {
    unsigned u = __float_as_uint(f);
    u += 0x7fffu + ((u >> 16) & 1u);   // round-to-nearest-even
    return u >> 16;
}
__device__ __forceinline__ unsigned pack_bf16(float lo, float hi) {
    return bf16r(lo) | (bf16r(hi) << 16);
}

// ---------------- degree count ----------------
__global__ void deg_kernel(const int* __restrict__ ei, int* __restrict__ deg, int E) {
    int e = blockIdx.x * blockDim.x + threadIdx.x;
    if (e < E) {
        int r = ei[e];
        int c = ei[E + e];
        if (r != c) atomicAdd(&deg[r], 1);
    }
}

// ---------------- dinv ----------------
__global__ void dinv_kernel(const int* __restrict__ deg, float* __restrict__ dinv, int n) {
    int i = blockIdx.x * blockDim.x + threadIdx.x;
    if (i < n) {
        int d = deg[i];
        dinv[i] = (d > 0) ? rsqrtf((float)d) : 0.f;
    }
}

// ---------------- exclusive scan -> row_ptr (single block) ----------------
__global__ __launch_bounds__(1024) void scan_kernel(const int* __restrict__ deg, int* __restrict__ row_ptr, int n) {
    __shared__ int wsums[16];
    __shared__ int s_chunk;
    __shared__ int s_carry;
    int t = threadIdx.x;
    if (t == 0) { s_carry = 0; row_ptr[0] = 0; }
    __syncthreads();
    for (int base = 0; base < n; base += 1024) {
        int idx = base + t;
        int v = (idx < n) ? deg[idx] : 0;
        int vi = v;
        #pragma unroll
        for (int off = 1; off < 64; off <<= 1) {
            int x = __shfl_up(vi, off);
            if ((t & 63) >= off) vi += x;
        }
        if ((t & 63) == 63) wsums[t >> 6] = vi;
        __syncthreads();
        if (t < 16) {
            int s = wsums[t];
            int si = s;
            #pragma unroll
            for (int off = 1; off < 16; off <<= 1) {
                int x = __shfl_up(si, off);
                if (t >= off) si += x;
            }
            wsums[t] = si - s;
            if (t == 15) s_chunk = si;
        }
        __syncthreads();
        if (idx < n) row_ptr[idx + 1] = s_carry + wsums[t >> 6] + vi;
        __syncthreads();
        if (t == 0) s_carry += s_chunk;
        __syncthreads();
    }
}

// ---------------- CSR fill with edge weights ----------------
__global__ void fill_kernel(const int* __restrict__ ei, const int* __restrict__ row_ptr,
                            int* __restrict__ fillc, const float* __restrict__ dinv,
                            int* __restrict__ e_col, float* __restrict__ e_w, int E) {
    int e = blockIdx.x * blockDim.x + threadIdx.x;
    if (e < E) {
        int r = ei[e];
        int c = ei[E + e];
        if (r != c) {
            int pos = row_ptr[r] + atomicAdd(&fillc[r], 1);
            e_col[pos] = c;
            e_w[pos] = -dinv[r] * dinv[c];
        }
    }
}

// ---------------- x (fp32) -> bf16x2-packed ----------------
__global__ void xconv_kernel(const float2* __restrict__ x, unsigned* __restrict__ xb, int n2) {
    int id = blockIdx.x * blockDim.x + threadIdx.x;
    if (id < n2) {
        float2 v = x[id];
        xb[id] = pack_bf16(v.x, v.y);
    }
}

// ---------------- W [3][128][128] fp32 -> Wt [3][n][k] bf16 (transposed) ----------------
__global__ void wprep_kernel(const float* __restrict__ W, unsigned short* __restrict__ Wt) {
    int id = blockIdx.x * blockDim.x + threadIdx.x;
    if (id < 3 * DFEAT * DFEAT) {
        int seg = id >> 14;
        int k   = (id >> 7) & 127;
        int nn  = id & 127;
        Wt[(seg << 14) + (nn << 7) + k] = (unsigned short)bf16r(W[id]);
    }
}

// ---------------- sparse prop (bf16 in/out, fp32 accumulate) ----------------
// 1 wave per node, 4 nodes per block; shuffle-broadcast (col,w); no LDS, no barriers.
// hout[i,:] = alpha * sum_e w_e * hin[col_e,:]  (- sub[i,:])
__global__ __launch_bounds__(256) void prop_bf16_kernel(
    const unsigned* __restrict__ hin, const unsigned* __restrict__ sub,
    unsigned* __restrict__ hout,
    const int* __restrict__ row_ptr, const int* __restrict__ e_col,
    const float* __restrict__ e_w, float alpha, int n)
{
    int node = blockIdx.x * 4 + (threadIdx.x >> 6);
    int t = threadIdx.x & 63;     // feature pair: features 2t, 2t+1
    if (node >= n) return;
    int s = row_ptr[node];
    int e = row_ptr[node + 1];
    float a0 = 0.f, a1 = 0.f;
    for (int base = s; base < e; base += 64) {
        int m = e - base; if (m > 64) m = 64;
        int colv = 0; float wv = 0.f;
        if (t < m) { colv = e_col[base + t]; wv = e_w[base + t]; }
        for (int j = 0; j < m; ++j) {
            int c = __shfl(colv, j);
            float w = __shfl(wv, j);
            unsigned v = hin[(size_t)c * 64 + t];
            a0 += w * __uint_as_float(v << 16);
            a1 += w * __uint_as_float(v & 0xffff0000u);
        }
    }
    a0 *= alpha; a1 *= alpha;
    if (sub) {
        unsigned v = sub[(size_t)node * 64 + t];
        a0 -= __uint_as_float(v << 16);
        a1 -= __uint_as_float(v & 0xffff0000u);
    }
    hout[(size_t)node * 64 + t] = pack_bf16(a0, a1);
}

// ---------------- fused 3-way MFMA GEMM + bias + ReLU ----------------
// out[i,:] = relu( X0[i,:]@W[0] + X1[i,:]@W[1] + X2[i,:]@W[2] + b )
// Block = 4 waves x 16 rows = 64 rows, full 128 cols. A-frags direct from
// global (16B contiguous, each row owned by one wave); B-frags from
// pre-transposed Wt[n][k] (L2-resident). No LDS, no barriers.
__global__ __launch_bounds__(256) void gemm3_mfma_kernel(
    const unsigned short* __restrict__ X0, const unsigned short* __restrict__ X1,
    const unsigned short* __restrict__ X2,
    const unsigned short* __restrict__ Wt, const float* __restrict__ bias,
    void* __restrict__ out, int n, int out_bf16)
{
    const int wave = threadIdx.x >> 6;
    const int lane = threadIdx.x & 63;
    const int quad = lane >> 4;
    const int l16  = lane & 15;

    int row = blockIdx.x * 64 + wave * 16 + l16;
    int rowc = row < n ? row : (n - 1);

    const unsigned short* Xps[3] = {X0, X1, X2};

    f32x4 acc[8];
    #pragma unroll
    for (int c = 0; c < 8; ++c) acc[c] = (f32x4){0.f, 0.f, 0.f, 0.f};

    #pragma unroll
    for (int seg = 0; seg < 3; ++seg) {
        const unsigned short* Xp = Xps[seg] + (size_t)rowc * DFEAT;
        const unsigned short* Wp = Wt + (seg << 14);
        #pragma unroll
        for (int kk = 0; kk < 4; ++kk) {
            const int ko = kk * 32 + quad * 8;
            bf16x8 a = *(const bf16x8*)(Xp + ko);
            #pragma unroll
            for (int c = 0; c < 8; ++c) {
                bf16x8 b = *(const bf16x8*)(Wp + (size_t)(c * 16 + l16) * DFEAT + ko);
                acc[c] = __builtin_amdgcn_mfma_f32_16x16x32_bf16(a, b, acc[c], 0, 0, 0);
            }
        }
    }

    // C/D layout: col = lane&15, row = quad*4 + reg
    int orow0 = blockIdx.x * 64 + wave * 16 + quad * 4;
    #pragma unroll
    for (int c = 0; c < 8; ++c) {
        int col = c * 16 + l16;
        float bv = bias[col];
        #pragma unroll
        for (int r = 0; r < 4; ++r) {
            int orow = orow0 + r;
            if (orow < n) {
                float v = fmaxf(acc[c][r] + bv, 0.f);
                if (out_bf16)
                    ((unsigned short*)out)[(size_t)orow * DFEAT + col] = (unsigned short)bf16r(v);
                else
                    ((float*)out)[(size_t)orow * DFEAT + col] = v;
            }
        }
    }
}

extern "C" void kernel_launch(void* const* d_in, const int* in_sizes, int n_in,
                              void* d_out, int out_size, void* d_ws, size_t ws_size,
                              hipStream_t stream) {
    const float* x  = (const float*)d_in[0];
    const int*   ei = (const int*)d_in[1];
    const float* W1 = (const float*)d_in[2];
    const float* b1 = (const float*)d_in[3];
    const float* W2 = (const float*)d_in[4];
    const float* b2 = (const float*)d_in[5];
    const float* W3 = (const float*)d_in[6];
    const float* b3 = (const float*)d_in[7];

    const int N = in_sizes[0] / DFEAT;   // 50000
    const int E = in_sizes[1] / 2;       // 800000
    const int NPK = N * (DFEAT / 2);     // packed bf16x2 words per array

    // workspace layout
    unsigned* xb  = (unsigned*)d_ws;
    unsigned* t1b = xb  + NPK;
    unsigned* t2b = t1b + NPK;
    unsigned* ab  = t2b + NPK;
    unsigned short* wt = (unsigned short*)(ab + NPK);   // 3 layers * 3*128*128
    int*   deg     = (int*)(wt + 3 * 3 * DFEAT * DFEAT);
    int*   fillc   = deg + N;
    int*   row_ptr = fillc + N;
    float* dinv    = (float*)(row_ptr + (N + 1));
    int*   e_col   = (int*)(dinv + N);
    float* e_w     = (float*)(e_col + E);

    hipMemsetAsync(deg,   0, sizeof(int) * N, stream);
    hipMemsetAsync(fillc, 0, sizeof(int) * N, stream);

    deg_kernel<<<(E + 255) / 256, 256, 0, stream>>>(ei, deg, E);
    scan_kernel<<<1, 1024, 0, stream>>>(deg, row_ptr, N);
    dinv_kernel<<<(N + 255) / 256, 256, 0, stream>>>(deg, dinv, N);
    fill_kernel<<<(E + 255) / 256, 256, 0, stream>>>(ei, row_ptr, fillc, dinv, e_col, e_w, E);

    xconv_kernel<<<(NPK + 255) / 256, 256, 0, stream>>>((const float2*)x, xb, NPK);
    const int WELEM = 3 * DFEAT * DFEAT;
    wprep_kernel<<<(WELEM + 255) / 256, 256, 0, stream>>>(W1, wt);
    wprep_kernel<<<(WELEM + 255) / 256, 256, 0, stream>>>(W2, wt + WELEM);
    wprep_kernel<<<(WELEM + 255) / 256, 256, 0, stream>>>(W3, wt + 2 * WELEM);

    const float* bl[3] = {b1, b2, b3};
    const unsigned* hin = xb;
    const int prop_grid = (N + 3) / 4;
    const int gemm_grid = (N + 63) / 64;
    for (int l = 0; l < 3; ++l) {
        // Tx1 = L_hat @ h
        prop_bf16_kernel<<<prop_grid, 256, 0, stream>>>(hin, nullptr, t1b, row_ptr, e_col, e_w, 1.f, N);
        // Tx2 = 2 * L_hat @ Tx1 - h
        prop_bf16_kernel<<<prop_grid, 256, 0, stream>>>(t1b, hin, t2b, row_ptr, e_col, e_w, 2.f, N);
        // out = relu(h@W0 + Tx1@W1 + Tx2@W2 + b)
        void* hout = (l == 2) ? d_out : (void*)ab;
        gemm3_mfma_kernel<<<gemm_grid, 256, 0, stream>>>(
            (const unsigned short*)hin, (const unsigned short*)t1b, (const unsigned short*)t2b,
            wt + l * WELEM, bl[l], hout, N, (l == 2) ? 0 : 1);
        hin = ab;
    }
}

// Round 3
// 435.181 us; speedup vs baseline: 2.5538x; 1.6646x over previous
//
#include <hip/hip_runtime.h>
#include <hip/hip_bf16.h>

#define DFEAT 128

typedef short bf16x8 __attribute__((ext_vector_type(8)));
typedef float f32x4  __attribute__((ext_vector_type(4)));
typedef unsigned short u16x8 __attribute__((ext_vector_type(8)));

__device__ __forceinline__ unsigned bf16r(float f) {
    unsigned u = __float_as_uint(f);
    u += 0x7fffu + ((u >> 16) & 1u);   // round-to-nearest-even
    return u >> 16;
}
__device__ __forceinline__ unsigned pack_bf16(float lo, float hi) {
    return bf16r(lo) | (bf16r(hi) << 16);
}

// ---------------- degree count ----------------
__global__ void deg_kernel(const int* __restrict__ ei, int* __restrict__ deg, int E) {
    int e = blockIdx.x * blockDim.x + threadIdx.x;
    if (e < E) {
        int r = ei[e];
        int c = ei[E + e];
        if (r != c) atomicAdd(&deg[r], 1);
    }
}

// ---------------- dinv ----------------
__global__ void dinv_kernel(const int* __restrict__ deg, float* __restrict__ dinv, int n) {
    int i = blockIdx.x * blockDim.x + threadIdx.x;
    if (i < n) {
        int d = deg[i];
        dinv[i] = (d > 0) ? rsqrtf((float)d) : 0.f;
    }
}

// ---------------- multi-block scan: stage 1 (block-local inclusive) ----------------
__global__ __launch_bounds__(1024) void scan1_kernel(const int* __restrict__ deg,
                                                     int* __restrict__ row_ptr,
                                                     int* __restrict__ bsum, int n) {
    __shared__ int wsums[16];
    int t = threadIdx.x;
    int idx = blockIdx.x * 1024 + t;
    int v = (idx < n) ? deg[idx] : 0;
    int vi = v;
    #pragma unroll
    for (int off = 1; off < 64; off <<= 1) {
        int x = __shfl_up(vi, off);
        if ((t & 63) >= off) vi += x;
    }
    if ((t & 63) == 63) wsums[t >> 6] = vi;
    __syncthreads();
    if (t < 16) {
        int s = wsums[t];
        int si = s;
        #pragma unroll
        for (int off = 1; off < 16; off <<= 1) {
            int x = __shfl_up(si, off);
            if (t >= off) si += x;
        }
        wsums[t] = si - s;              // exclusive prefix of wave sums
        if (t == 15) bsum[blockIdx.x] = si;  // block total
    }
    __syncthreads();
    if (idx < n) row_ptr[idx + 1] = wsums[t >> 6] + vi;   // block-local inclusive
}

// ---------------- scan stage 2: exclusive scan of block sums (1 wave) ----------------
__global__ void scan2_kernel(int* __restrict__ bsum, int nb) {
    int t = threadIdx.x;   // 64 threads
    int carry = 0;
    for (int base = 0; base < nb; base += 64) {
        int v = (base + t < nb) ? bsum[base + t] : 0;
        int vi = v;
        #pragma unroll
        for (int off = 1; off < 64; off <<= 1) {
            int x = __shfl_up(vi, off);
            if (t >= off) vi += x;
        }
        if (base + t < nb) bsum[base + t] = carry + vi - v;  // exclusive
        carry += __shfl(vi, 63);
    }
}

// ---------------- scan stage 3: add block offsets ----------------
__global__ __launch_bounds__(1024) void scan3_kernel(int* __restrict__ row_ptr,
                                                     const int* __restrict__ bsum, int n) {
    int idx = blockIdx.x * 1024 + threadIdx.x;
    if (idx == 0) row_ptr[0] = 0;
    if (idx < n) row_ptr[idx + 1] += bsum[blockIdx.x];
}

// ---------------- CSR fill with edge weights ----------------
__global__ void fill_kernel(const int* __restrict__ ei, const int* __restrict__ row_ptr,
                            int* __restrict__ fillc, const float* __restrict__ dinv,
                            int* __restrict__ e_col, float* __restrict__ e_w, int E) {
    int e = blockIdx.x * blockDim.x + threadIdx.x;
    if (e < E) {
        int r = ei[e];
        int c = ei[E + e];
        if (r != c) {
            int pos = row_ptr[r] + atomicAdd(&fillc[r], 1);
            e_col[pos] = c;
            e_w[pos] = -dinv[r] * dinv[c];
        }
    }
}

// ---------------- x (fp32) -> bf16x2-packed ----------------
__global__ void xconv_kernel(const float2* __restrict__ x, unsigned* __restrict__ xb, int n2) {
    int id = blockIdx.x * blockDim.x + threadIdx.x;
    if (id < n2) {
        float2 v = x[id];
        xb[id] = pack_bf16(v.x, v.y);
    }
}

// ---------------- W1/2/3 [3][128][128] fp32 -> Wt [layer][seg][n][k] bf16 ----------------
__global__ void wprep_kernel(const float* __restrict__ W1, const float* __restrict__ W2,
                             const float* __restrict__ W3, unsigned short* __restrict__ Wt) {
    int id = blockIdx.x * blockDim.x + threadIdx.x;
    const int PER = 3 * DFEAT * DFEAT;
    if (id < 3 * PER) {
        int layer = id / PER;
        int rem = id - layer * PER;
        const float* W = (layer == 0) ? W1 : ((layer == 1) ? W2 : W3);
        int seg = rem >> 14;
        int k   = (rem >> 7) & 127;
        int nn  = rem & 127;
        Wt[layer * PER + (seg << 14) + (nn << 7) + k] = (unsigned short)bf16r(W[rem]);
    }
}

// ---------------- sparse prop (bf16 in/out, fp32 accumulate) ----------------
// 1 wave per node; node forced wave-uniform -> edge metadata via scalar loads;
// unroll x8 for 8 outstanding gathers per wave.
__global__ __launch_bounds__(256) void prop_bf16_kernel(
    const unsigned* __restrict__ hin, const unsigned* __restrict__ sub,
    unsigned* __restrict__ hout,
    const int* __restrict__ row_ptr, const int* __restrict__ e_col,
    const float* __restrict__ e_w, float alpha, int n)
{
    int wv = __builtin_amdgcn_readfirstlane(threadIdx.x >> 6);
    int node = blockIdx.x * 4 + wv;
    int t = threadIdx.x & 63;     // feature pair: features 2t, 2t+1
    if (node >= n) return;
    int s = row_ptr[node];
    int e = row_ptr[node + 1];
    float a0 = 0.f, a1 = 0.f;
    int j = s;
    for (; j + 8 <= e; j += 8) {
        int c0 = e_col[j+0], c1 = e_col[j+1], c2 = e_col[j+2], c3 = e_col[j+3];
        int c4 = e_col[j+4], c5 = e_col[j+5], c6 = e_col[j+6], c7 = e_col[j+7];
        float w0 = e_w[j+0], w1 = e_w[j+1], w2 = e_w[j+2], w3 = e_w[j+3];
        float w4 = e_w[j+4], w5 = e_w[j+5], w6 = e_w[j+6], w7 = e_w[j+7];
        unsigned v0 = hin[(size_t)c0 * 64 + t];
        unsigned v1 = hin[(size_t)c1 * 64 + t];
        unsigned v2 = hin[(size_t)c2 * 64 + t];
        unsigned v3 = hin[(size_t)c3 * 64 + t];
        unsigned v4 = hin[(size_t)c4 * 64 + t];
        unsigned v5 = hin[(size_t)c5 * 64 + t];
        unsigned v6 = hin[(size_t)c6 * 64 + t];
        unsigned v7 = hin[(size_t)c7 * 64 + t];
        a0 += w0 * __uint_as_float(v0 << 16);  a1 += w0 * __uint_as_float(v0 & 0xffff0000u);
        a0 += w1 * __uint_as_float(v1 << 16);  a1 += w1 * __uint_as_float(v1 & 0xffff0000u);
        a0 += w2 * __uint_as_float(v2 << 16);  a1 += w2 * __uint_as_float(v2 & 0xffff0000u);
        a0 += w3 * __uint_as_float(v3 << 16);  a1 += w3 * __uint_as_float(v3 & 0xffff0000u);
        a0 += w4 * __uint_as_float(v4 << 16);  a1 += w4 * __uint_as_float(v4 & 0xffff0000u);
        a0 += w5 * __uint_as_float(v5 << 16);  a1 += w5 * __uint_as_float(v5 & 0xffff0000u);
        a0 += w6 * __uint_as_float(v6 << 16);  a1 += w6 * __uint_as_float(v6 & 0xffff0000u);
        a0 += w7 * __uint_as_float(v7 << 16);  a1 += w7 * __uint_as_float(v7 & 0xffff0000u);
    }
    for (; j < e; ++j) {
        int c = e_col[j];
        float w = e_w[j];
        unsigned v = hin[(size_t)c * 64 + t];
        a0 += w * __uint_as_float(v << 16);
        a1 += w * __uint_as_float(v & 0xffff0000u);
    }
    a0 *= alpha; a1 *= alpha;
    if (sub) {
        unsigned v = sub[(size_t)node * 64 + t];
        a0 -= __uint_as_float(v << 16);
        a1 -= __uint_as_float(v & 0xffff0000u);
    }
    hout[(size_t)node * 64 + t] = pack_bf16(a0, a1);
}

// ---------------- fused 3-way MFMA GEMM + bias + ReLU ----------------
// out[i,:] = relu( X0@W[0] + X1@W[1] + X2@W[2] + b ) row-block 128, block=4 waves,
// each wave owns 2 row-tiles (32 rows). W staged in LDS per seg (pad +8 -> only
// free 2-way bank aliasing). A-frags direct from global.
#define WPAD 136
__global__ __launch_bounds__(256) void gemm3_mfma_kernel(
    const unsigned short* __restrict__ X0, const unsigned short* __restrict__ X1,
    const unsigned short* __restrict__ X2,
    const unsigned short* __restrict__ Wt, const float* __restrict__ bias,
    void* __restrict__ out, int n, int out_bf16)
{
    __shared__ unsigned short Ws[DFEAT * WPAD];   // 34816 B
    const int t    = threadIdx.x;
    const int wave = t >> 6;
    const int lane = t & 63;
    const int quad = lane >> 4;
    const int l16  = lane & 15;

    const int row_base = blockIdx.x * 128 + wave * 32;
    int r0 = row_base + l16;       if (r0 >= n) r0 = n - 1;
    int r1 = row_base + 16 + l16;  if (r1 >= n) r1 = n - 1;

    const unsigned short* Xps[3] = {X0, X1, X2};

    f32x4 acc[2][8];
    #pragma unroll
    for (int tt = 0; tt < 2; ++tt)
        #pragma unroll
        for (int c = 0; c < 8; ++c) acc[tt][c] = (f32x4){0.f, 0.f, 0.f, 0.f};

    const int srow = t >> 1;            // staging: row 0..127
    const int shalf = (t & 1) * 64;     // half-row

    #pragma unroll
    for (int seg = 0; seg < 3; ++seg) {
        __syncthreads();   // previous seg fully consumed
        const unsigned short* Wp = Wt + (seg << 14);
        #pragma unroll
        for (int i = 0; i < 8; ++i) {
            *(u16x8*)&Ws[srow * WPAD + shalf + i * 8] =
                *(const u16x8*)&Wp[srow * DFEAT + shalf + i * 8];
        }
        __syncthreads();
        const unsigned short* A0 = Xps[seg] + (size_t)r0 * DFEAT;
        const unsigned short* A1 = Xps[seg] + (size_t)r1 * DFEAT;
        #pragma unroll
        for (int kk = 0; kk < 4; ++kk) {
            const int ko = kk * 32 + quad * 8;
            bf16x8 a0 = *(const bf16x8*)(A0 + ko);
            bf16x8 a1 = *(const bf16x8*)(A1 + ko);
            #pragma unroll
            for (int c = 0; c < 8; ++c) {
                bf16x8 b = *(const bf16x8*)&Ws[(c * 16 + l16) * WPAD + ko];
                acc[0][c] = __builtin_amdgcn_mfma_f32_16x16x32_bf16(a0, b, acc[0][c], 0, 0, 0);
                acc[1][c] = __builtin_amdgcn_mfma_f32_16x16x32_bf16(a1, b, acc[1][c], 0, 0, 0);
            }
        }
    }

    // C/D layout: col = lane&15, row = quad*4 + reg
    #pragma unroll
    for (int tt = 0; tt < 2; ++tt) {
        int orow0 = blockIdx.x * 128 + wave * 32 + tt * 16 + quad * 4;
        #pragma unroll
        for (int c = 0; c < 8; ++c) {
            int col = c * 16 + l16;
            float bv = bias[col];
            #pragma unroll
            for (int r = 0; r < 4; ++r) {
                int orow = orow0 + r;
                if (orow < n) {
                    float v = fmaxf(acc[tt][c][r] + bv, 0.f);
                    if (out_bf16)
                        ((unsigned short*)out)[(size_t)orow * DFEAT + col] = (unsigned short)bf16r(v);
                    else
                        ((float*)out)[(size_t)orow * DFEAT + col] = v;
                }
            }
        }
    }
}

extern "C" void kernel_launch(void* const* d_in, const int* in_sizes, int n_in,
                              void* d_out, int out_size, void* d_ws, size_t ws_size,
                              hipStream_t stream) {
    const float* x  = (const float*)d_in[0];
    const int*   ei = (const int*)d_in[1];
    const float* W1 = (const float*)d_in[2];
    const float* b1 = (const float*)d_in[3];
    const float* W2 = (const float*)d_in[4];
    const float* b2 = (const float*)d_in[5];
    const float* W3 = (const float*)d_in[6];
    const float* b3 = (const float*)d_in[7];

    const int N = in_sizes[0] / DFEAT;   // 50000
    const int E = in_sizes[1] / 2;       // 800000
    const int NPK = N * (DFEAT / 2);     // packed bf16x2 words per array
    const int NB = (N + 1023) / 1024;    // scan blocks

    // workspace layout
    unsigned* xb  = (unsigned*)d_ws;
    unsigned* t1b = xb  + NPK;
    unsigned* t2b = t1b + NPK;
    unsigned* ab  = t2b + NPK;
    unsigned short* wt = (unsigned short*)(ab + NPK);   // 3 layers * 3*128*128
    int*   deg     = (int*)(wt + 3 * 3 * DFEAT * DFEAT);
    int*   fillc   = deg + N;
    int*   row_ptr = fillc + N;
    float* dinv    = (float*)(row_ptr + (N + 1));
    int*   e_col   = (int*)(dinv + N);
    float* e_w     = (float*)(e_col + E);
    int*   bsum    = (int*)(e_w + E);

    hipMemsetAsync(deg,   0, sizeof(int) * N, stream);
    hipMemsetAsync(fillc, 0, sizeof(int) * N, stream);

    deg_kernel<<<(E + 255) / 256, 256, 0, stream>>>(ei, deg, E);
    scan1_kernel<<<NB, 1024, 0, stream>>>(deg, row_ptr, bsum, N);
    scan2_kernel<<<1, 64, 0, stream>>>(bsum, NB);
    scan3_kernel<<<NB, 1024, 0, stream>>>(row_ptr, bsum, N);
    dinv_kernel<<<(N + 255) / 256, 256, 0, stream>>>(deg, dinv, N);
    fill_kernel<<<(E + 255) / 256, 256, 0, stream>>>(ei, row_ptr, fillc, dinv, e_col, e_w, E);

    xconv_kernel<<<(NPK + 255) / 256, 256, 0, stream>>>((const float2*)x, xb, NPK);
    const int WELEM = 3 * DFEAT * DFEAT;
    wprep_kernel<<<(3 * WELEM + 255) / 256, 256, 0, stream>>>(W1, W2, W3, wt);

    const float* bl[3] = {b1, b2, b3};
    const unsigned* hin = xb;
    const int prop_grid = (N + 3) / 4;
    const int gemm_grid = (N + 127) / 128;
    for (int l = 0; l < 3; ++l) {
        // Tx1 = L_hat @ h
        prop_bf16_kernel<<<prop_grid, 256, 0, stream>>>(hin, nullptr, t1b, row_ptr, e_col, e_w, 1.f, N);
        // Tx2 = 2 * L_hat @ Tx1 - h
        prop_bf16_kernel<<<prop_grid, 256, 0, stream>>>(t1b, hin, t2b, row_ptr, e_col, e_w, 2.f, N);
        // out = relu(h@W0 + Tx1@W1 + Tx2@W2 + b)
        void* hout = (l == 2) ? d_out : (void*)ab;
        gemm3_mfma_kernel<<<gemm_grid, 256, 0, stream>>>(
            (const unsigned short*)hin, (const unsigned short*)t1b, (const unsigned short*)t2b,
            wt + l * WELEM, bl[l], hout, N, (l == 2) ? 0 : 1);
        hin = ab;
    }
}

// Round 4
// 409.483 us; speedup vs baseline: 2.7141x; 1.0628x over previous
//
#include <hip/hip_runtime.h>
#include <hip/hip_bf16.h>

#define DFEAT 128

typedef short bf16x8 __attribute__((ext_vector_type(8)));
typedef float f32x4  __attribute__((ext_vector_type(4)));
typedef unsigned short u16x8 __attribute__((ext_vector_type(8)));

__device__ __forceinline__ unsigned bf16r(float f) {
    unsigned u = __float_as_uint(f);
    u += 0x7fffu + ((u >> 16) & 1u);   // round-to-nearest-even
    return u >> 16;
}
__device__ __forceinline__ unsigned pack_bf16(float lo, float hi) {
    return bf16r(lo) | (bf16r(hi) << 16);
}

// ---------------- degree count (XCD-privatized, fire-and-forget atomics) ----------------
__global__ void deg_kernel(const int* __restrict__ ei, int* __restrict__ deg8, int E, int N) {
    int e = blockIdx.x * blockDim.x + threadIdx.x;
    if (e < E) {
        int r = ei[e];
        int c = ei[E + e];
        if (r != c) atomicAdd(&deg8[(blockIdx.x & 7) * N + r], 1);
    }
}

// ---------------- scan stage 1: sum deg8 -> dinv, poff, block-local inclusive scan ----------------
__global__ __launch_bounds__(1024) void scan1_kernel(const int* __restrict__ deg8,
                                                     int* __restrict__ poff,
                                                     int* __restrict__ row_ptr,
                                                     int* __restrict__ bsum,
                                                     float* __restrict__ dinv, int n) {
    __shared__ int wsums[16];
    int t = threadIdx.x;
    int idx = blockIdx.x * 1024 + t;
    int tot = 0;
    if (idx < n) {
        int run = 0;
        #pragma unroll
        for (int p = 0; p < 8; ++p) {
            int d = deg8[p * n + idx];
            poff[p * n + idx] = run;
            run += d;
        }
        tot = run;
        dinv[idx] = (tot > 0) ? rsqrtf((float)tot) : 0.f;
    }
    int vi = tot;
    #pragma unroll
    for (int off = 1; off < 64; off <<= 1) {
        int x = __shfl_up(vi, off);
        if ((t & 63) >= off) vi += x;
    }
    if ((t & 63) == 63) wsums[t >> 6] = vi;
    __syncthreads();
    if (t < 16) {
        int s = wsums[t];
        int si = s;
        #pragma unroll
        for (int off = 1; off < 16; off <<= 1) {
            int x = __shfl_up(si, off);
            if (t >= off) si += x;
        }
        wsums[t] = si - s;                  // exclusive prefix of wave sums
        if (t == 15) bsum[blockIdx.x] = si; // block total
    }
    __syncthreads();
    if (idx < n) row_ptr[idx + 1] = wsums[t >> 6] + vi;   // block-local inclusive
}

// ---------------- scan stage 2: exclusive scan of block sums (1 wave) ----------------
__global__ void scan2_kernel(int* __restrict__ bsum, int nb) {
    int t = threadIdx.x;   // 64 threads
    int carry = 0;
    for (int base = 0; base < nb; base += 64) {
        int v = (base + t < nb) ? bsum[base + t] : 0;
        int vi = v;
        #pragma unroll
        for (int off = 1; off < 64; off <<= 1) {
            int x = __shfl_up(vi, off);
            if (t >= off) vi += x;
        }
        if (base + t < nb) bsum[base + t] = carry + vi - v;  // exclusive
        carry += __shfl(vi, 63);
    }
}

// ---------------- scan stage 3: add block offsets ----------------
__global__ __launch_bounds__(1024) void scan3_kernel(int* __restrict__ row_ptr,
                                                     const int* __restrict__ bsum, int n) {
    int idx = blockIdx.x * 1024 + threadIdx.x;
    if (idx == 0) row_ptr[0] = 0;
    if (idx < n) row_ptr[idx + 1] += bsum[blockIdx.x];
}

// ---------------- CSR fill: packed (col:u16 | w:f16) ----------------
__global__ void fill_kernel(const int* __restrict__ ei, const int* __restrict__ row_ptr,
                            const int* __restrict__ poff, int* __restrict__ fillc8,
                            const float* __restrict__ dinv,
                            unsigned* __restrict__ e_cw, int E, int N) {
    int e = blockIdx.x * blockDim.x + threadIdx.x;
    if (e < E) {
        int r = ei[e];
        int c = ei[E + e];
        if (r != c) {
            int p = blockIdx.x & 7;
            int k = atomicAdd(&fillc8[p * N + r], 1);
            int pos = row_ptr[r] + poff[p * N + r] + k;
            float w = -dinv[r] * dinv[c];
            _Float16 hf = (_Float16)w;
            unsigned short wb;
            __builtin_memcpy(&wb, &hf, 2);
            e_cw[pos] = (unsigned)c | ((unsigned)wb << 16);
        }
    }
}

// ---------------- x (fp32) -> bf16x2-packed ----------------
__global__ void xconv_kernel(const float2* __restrict__ x, unsigned* __restrict__ xb, int n2) {
    int id = blockIdx.x * blockDim.x + threadIdx.x;
    if (id < n2) {
        float2 v = x[id];
        xb[id] = pack_bf16(v.x, v.y);
    }
}

// ---------------- W1/2/3 [3][128][128] fp32 -> Wt [layer][seg][n][k] bf16 ----------------
__global__ void wprep_kernel(const float* __restrict__ W1, const float* __restrict__ W2,
                             const float* __restrict__ W3, unsigned short* __restrict__ Wt) {
    int id = blockIdx.x * blockDim.x + threadIdx.x;
    const int PER = 3 * DFEAT * DFEAT;
    if (id < 3 * PER) {
        int layer = id / PER;
        int rem = id - layer * PER;
        const float* W = (layer == 0) ? W1 : ((layer == 1) ? W2 : W3);
        int seg = rem >> 14;
        int k   = (rem >> 7) & 127;
        int nn  = rem & 127;
        Wt[layer * PER + (seg << 14) + (nn << 7) + k] = (unsigned short)bf16r(W[rem]);
    }
}

// ---------------- sparse prop (bf16 in/out, fp32 accumulate) ----------------
// 1 wave per node (wave-uniform node -> scalar metadata loads); 16-wide
// load-then-FMA phases for 16 outstanding gathers per wave.
__global__ __launch_bounds__(256) void prop_bf16_kernel(
    const unsigned* __restrict__ hin, const unsigned* __restrict__ sub,
    unsigned* __restrict__ hout,
    const int* __restrict__ row_ptr, const unsigned* __restrict__ e_cw,
    float alpha, int n)
{
    int wv = __builtin_amdgcn_readfirstlane(threadIdx.x >> 6);
    int node = blockIdx.x * 4 + wv;
    int t = threadIdx.x & 63;     // feature pair: features 2t, 2t+1
    if (node >= n) return;
    int s = row_ptr[node];
    int e = row_ptr[node + 1];
    float a0 = 0.f, a1 = 0.f;
    int j = s;
    for (; j + 16 <= e; j += 16) {
        unsigned cw[16];
        #pragma unroll
        for (int q = 0; q < 16; ++q) cw[q] = e_cw[j + q];
        unsigned v[16];
        #pragma unroll
        for (int q = 0; q < 16; ++q)
            v[q] = hin[(size_t)(cw[q] & 0xffffu) * 64 + t];
        #pragma unroll
        for (int q = 0; q < 16; ++q) {
            unsigned short wb = (unsigned short)(cw[q] >> 16);
            _Float16 hf; __builtin_memcpy(&hf, &wb, 2);
            float w = (float)hf;
            a0 += w * __uint_as_float(v[q] << 16);
            a1 += w * __uint_as_float(v[q] & 0xffff0000u);
        }
    }
    for (; j + 4 <= e; j += 4) {
        unsigned cw[4];
        #pragma unroll
        for (int q = 0; q < 4; ++q) cw[q] = e_cw[j + q];
        unsigned v[4];
        #pragma unroll
        for (int q = 0; q < 4; ++q)
            v[q] = hin[(size_t)(cw[q] & 0xffffu) * 64 + t];
        #pragma unroll
        for (int q = 0; q < 4; ++q) {
            unsigned short wb = (unsigned short)(cw[q] >> 16);
            _Float16 hf; __builtin_memcpy(&hf, &wb, 2);
            float w = (float)hf;
            a0 += w * __uint_as_float(v[q] << 16);
            a1 += w * __uint_as_float(v[q] & 0xffff0000u);
        }
    }
    for (; j < e; ++j) {
        unsigned cwv = e_cw[j];
        unsigned short wb = (unsigned short)(cwv >> 16);
        _Float16 hf; __builtin_memcpy(&hf, &wb, 2);
        float w = (float)hf;
        unsigned v = hin[(size_t)(cwv & 0xffffu) * 64 + t];
        a0 += w * __uint_as_float(v << 16);
        a1 += w * __uint_as_float(v & 0xffff0000u);
    }
    a0 *= alpha; a1 *= alpha;
    if (sub) {
        unsigned v = sub[(size_t)node * 64 + t];
        a0 -= __uint_as_float(v << 16);
        a1 -= __uint_as_float(v & 0xffff0000u);
    }
    hout[(size_t)node * 64 + t] = pack_bf16(a0, a1);
}

// ---------------- fused 3-way MFMA GEMM + bias + ReLU ----------------
#define WPAD 136
__global__ __launch_bounds__(256) void gemm3_mfma_kernel(
    const unsigned short* __restrict__ X0, const unsigned short* __restrict__ X1,
    const unsigned short* __restrict__ X2,
    const unsigned short* __restrict__ Wt, const float* __restrict__ bias,
    void* __restrict__ out, int n, int out_bf16)
{
    __shared__ unsigned short Ws[DFEAT * WPAD];   // 34816 B
    const int t    = threadIdx.x;
    const int wave = t >> 6;
    const int lane = t & 63;
    const int quad = lane >> 4;
    const int l16  = lane & 15;

    const int row_base = blockIdx.x * 128 + wave * 32;
    int r0 = row_base + l16;       if (r0 >= n) r0 = n - 1;
    int r1 = row_base + 16 + l16;  if (r1 >= n) r1 = n - 1;

    const unsigned short* Xps[3] = {X0, X1, X2};

    f32x4 acc[2][8];
    #pragma unroll
    for (int tt = 0; tt < 2; ++tt)
        #pragma unroll
        for (int c = 0; c < 8; ++c) acc[tt][c] = (f32x4){0.f, 0.f, 0.f, 0.f};

    const int srow = t >> 1;            // staging: row 0..127
    const int shalf = (t & 1) * 64;     // half-row

    #pragma unroll
    for (int seg = 0; seg < 3; ++seg) {
        __syncthreads();   // previous seg fully consumed
        const unsigned short* Wp = Wt + (seg << 14);
        #pragma unroll
        for (int i = 0; i < 8; ++i) {
            *(u16x8*)&Ws[srow * WPAD + shalf + i * 8] =
                *(const u16x8*)&Wp[srow * DFEAT + shalf + i * 8];
        }
        __syncthreads();
        const unsigned short* A0 = Xps[seg] + (size_t)r0 * DFEAT;
        const unsigned short* A1 = Xps[seg] + (size_t)r1 * DFEAT;
        #pragma unroll
        for (int kk = 0; kk < 4; ++kk) {
            const int ko = kk * 32 + quad * 8;
            bf16x8 a0 = *(const bf16x8*)(A0 + ko);
            bf16x8 a1 = *(const bf16x8*)(A1 + ko);
            #pragma unroll
            for (int c = 0; c < 8; ++c) {
                bf16x8 b = *(const bf16x8*)&Ws[(c * 16 + l16) * WPAD + ko];
                acc[0][c] = __builtin_amdgcn_mfma_f32_16x16x32_bf16(a0, b, acc[0][c], 0, 0, 0);
                acc[1][c] = __builtin_amdgcn_mfma_f32_16x16x32_bf16(a1, b, acc[1][c], 0, 0, 0);
            }
        }
    }

    // C/D layout: col = lane&15, row = quad*4 + reg
    #pragma unroll
    for (int tt = 0; tt < 2; ++tt) {
        int orow0 = blockIdx.x * 128 + wave * 32 + tt * 16 + quad * 4;
        #pragma unroll
        for (int c = 0; c < 8; ++c) {
            int col = c * 16 + l16;
            float bv = bias[col];
            #pragma unroll
            for (int r = 0; r < 4; ++r) {
                int orow = orow0 + r;
                if (orow < n) {
                    float v = fmaxf(acc[tt][c][r] + bv, 0.f);
                    if (out_bf16)
                        ((unsigned short*)out)[(size_t)orow * DFEAT + col] = (unsigned short)bf16r(v);
                    else
                        ((float*)out)[(size_t)orow * DFEAT + col] = v;
                }
            }
        }
    }
}

extern "C" void kernel_launch(void* const* d_in, const int* in_sizes, int n_in,
                              void* d_out, int out_size, void* d_ws, size_t ws_size,
                              hipStream_t stream) {
    const float* x  = (const float*)d_in[0];
    const int*   ei = (const int*)d_in[1];
    const float* W1 = (const float*)d_in[2];
    const float* b1 = (const float*)d_in[3];
    const float* W2 = (const float*)d_in[4];
    const float* b2 = (const float*)d_in[5];
    const float* W3 = (const float*)d_in[6];
    const float* b3 = (const float*)d_in[7];

    const int N = in_sizes[0] / DFEAT;   // 50000
    const int E = in_sizes[1] / 2;       // 800000
    const int NPK = N * (DFEAT / 2);     // packed bf16x2 words per array
    const int NB = (N + 1023) / 1024;    // scan blocks

    // workspace layout
    unsigned* xb  = (unsigned*)d_ws;
    unsigned* t1b = xb  + NPK;
    unsigned* t2b = t1b + NPK;
    unsigned* ab  = t2b + NPK;
    unsigned short* wt = (unsigned short*)(ab + NPK);   // 3 layers * 3*128*128
    int*   deg8    = (int*)(wt + 3 * 3 * DFEAT * DFEAT);
    int*   poff    = deg8 + 8 * N;
    int*   fillc8  = poff + 8 * N;
    int*   row_ptr = fillc8 + 8 * N;
    float* dinv    = (float*)(row_ptr + (N + 1));
    unsigned* e_cw = (unsigned*)(dinv + N);
    int*   bsum    = (int*)(e_cw + E);

    hipMemsetAsync(deg8,   0, sizeof(int) * 8 * N, stream);
    hipMemsetAsync(fillc8, 0, sizeof(int) * 8 * N, stream);

    deg_kernel<<<(E + 255) / 256, 256, 0, stream>>>(ei, deg8, E, N);
    scan1_kernel<<<NB, 1024, 0, stream>>>(deg8, poff, row_ptr, bsum, dinv, N);
    scan2_kernel<<<1, 64, 0, stream>>>(bsum, NB);
    scan3_kernel<<<NB, 1024, 0, stream>>>(row_ptr, bsum, N);
    fill_kernel<<<(E + 255) / 256, 256, 0, stream>>>(ei, row_ptr, poff, fillc8, dinv, e_cw, E, N);

    xconv_kernel<<<(NPK + 255) / 256, 256, 0, stream>>>((const float2*)x, xb, NPK);
    const int WELEM = 3 * DFEAT * DFEAT;
    wprep_kernel<<<(3 * WELEM + 255) / 256, 256, 0, stream>>>(W1, W2, W3, wt);

    const float* bl[3] = {b1, b2, b3};
    const unsigned* hin = xb;
    const int prop_grid = (N + 3) / 4;
    const int gemm_grid = (N + 127) / 128;
    for (int l = 0; l < 3; ++l) {
        // Tx1 = L_hat @ h
        prop_bf16_kernel<<<prop_grid, 256, 0, stream>>>(hin, nullptr, t1b, row_ptr, e_cw, 1.f, N);
        // Tx2 = 2 * L_hat @ Tx1 - h
        prop_bf16_kernel<<<prop_grid, 256, 0, stream>>>(t1b, hin, t2b, row_ptr, e_cw, 2.f, N);
        // out = relu(h@W0 + Tx1@W1 + Tx2@W2 + b)
        void* hout = (l == 2) ? d_out : (void*)ab;
        gemm3_mfma_kernel<<<gemm_grid, 256, 0, stream>>>(
            (const unsigned short*)hin, (const unsigned short*)t1b, (const unsigned short*)t2b,
            wt + l * WELEM, bl[l], hout, N, (l == 2) ? 0 : 1);
        hin = ab;
    }
}